// Round 1
// 109.474 us; speedup vs baseline: 1.0356x; 1.0356x over previous
//
#include <hip/hip_runtime.h>
#include <hip/hip_fp16.h>

#define N_NODES 50000
#define DIM 64
#define CB 391          // coarse buckets = ceil(N/128); bucket = dst >> 7
#define CAP 2560        // per-bucket capacity (mean 2046, sd ~45 -> +11 sd)
#define EPT 12          // edges per thread in partition (register-staged)
#define EB (512 * EPT)  // 6144 edges per partition block -> 131 blocks
#define BINCAP 64       // per-node LDS edge slots (deg: mean 16 sd 4 -> z=12)

typedef _Float16 half8 __attribute__((ext_vector_type(8)));
typedef float floatx4 __attribute__((ext_vector_type(4)));

// Workspace byte offsets (16B-aligned).
#define WS_CURSOR  0                          // CB ints (2 KB reserved)
#define WS_COARSE  2048                       // CB*CAP uint = 4,003,840
#define WS_YH      (WS_COARSE + 4003840)      // N*DIM f16 = 6,400,000 (y = x@W)

// ---------------------------------------------------------------------------
// Prep (512 thr): blocks [0,pa): SINGLE-PASS partition (register-staged,
// EPT=12/thread): hist -> reserve -> scatter.  Edge packed (src<<7)|(dst&127).
// Blocks [pa, pa+391): y = x @ W in fp16.  Projection commutes with the
// segment-sum ((agg+x)@W = segsum(x@W)+x@W), so fused needs NO MFMA phase.
// Each GEMM block: 8 waves x 16 rows, W^T staged in LDS (stride 80 halves:
// 160 B rows keep half8 reads 16B-aligned, spread banks).
// ---------------------------------------------------------------------------
__global__ void __launch_bounds__(512) prep_kernel(
        const float* __restrict__ x, const float* __restrict__ W,
        const int* __restrict__ edge_src, const int* __restrict__ edge_dst,
        int* __restrict__ cursor, unsigned int* __restrict__ coarse,
        _Float16* __restrict__ yh, int E, int pa) {
    int b = blockIdx.x, t = threadIdx.x;
    if (b < pa) {
        __shared__ int lhist[CB];
        __shared__ int lbase[CB];
        for (int i = t; i < CB; i += 512) lhist[i] = 0;
        __syncthreads();

        int base = b * EB;
        unsigned int pk[EPT];
        int bk[EPT];
        #pragma unroll
        for (int j = 0; j < EPT; ++j) {
            int e = base + j * 512 + t;       // coalesced
            bk[j] = -1;
            if (e < E) {
                int s = edge_src[e];
                int d = edge_dst[e];
                bk[j] = d >> 7;
                pk[j] = ((unsigned int)s << 7) | (unsigned int)(d & 127);
                atomicAdd(&lhist[bk[j]], 1);
            }
        }
        __syncthreads();
        for (int i = t; i < CB; i += 512) {
            lbase[i] = atomicAdd(&cursor[i], lhist[i]);
            lhist[i] = 0;
        }
        __syncthreads();
        #pragma unroll
        for (int j = 0; j < EPT; ++j) {
            if (bk[j] >= 0) {
                int r = atomicAdd(&lhist[bk[j]], 1);
                coarse[(size_t)bk[j] * CAP + lbase[bk[j]] + r] = pk[j];
            }
        }
    } else {
        // --- GEMM: yh[row] = fp16(x[row] @ W), 128 rows per block ---
        __shared__ _Float16 wh[64 * 80];      // wh[n*80+k] = W[k][n], 10.24 KB
        #pragma unroll
        for (int i = 0; i < 8; ++i) {
            int idx = i * 512 + t;            // coalesced read of W
            int k = idx >> 6, n = idx & 63;
            wh[n * 80 + k] = (_Float16)W[idx];
        }
        __syncthreads();

        int wv = t >> 6, lane = t & 63;
        int m = lane & 15, q = lane >> 4;
        int rbase = (b - pa) * 128 + wv * 16;
        int row = rbase + m;
        int rowc = row < N_NODES ? row : N_NODES - 1;   // clamp OOB loads
        const float* xp = x + (size_t)rowc * DIM + q * 8;
        float4 f0 = *reinterpret_cast<const float4*>(xp);
        float4 f1 = *reinterpret_cast<const float4*>(xp + 4);
        float4 f2 = *reinterpret_cast<const float4*>(xp + 32);
        float4 f3 = *reinterpret_cast<const float4*>(xp + 36);
        half8 a0 = {(_Float16)f0.x, (_Float16)f0.y, (_Float16)f0.z, (_Float16)f0.w,
                    (_Float16)f1.x, (_Float16)f1.y, (_Float16)f1.z, (_Float16)f1.w};
        half8 a1 = {(_Float16)f2.x, (_Float16)f2.y, (_Float16)f2.z, (_Float16)f2.w,
                    (_Float16)f3.x, (_Float16)f3.y, (_Float16)f3.z, (_Float16)f3.w};

        floatx4 accp[4];
        #pragma unroll
        for (int tt = 0; tt < 4; ++tt) {
            half8 bb0 = *reinterpret_cast<const half8*>(&wh[(tt * 16 + m) * 80 + q * 8]);
            half8 bb1 = *reinterpret_cast<const half8*>(&wh[(tt * 16 + m) * 80 + 32 + q * 8]);
            floatx4 cf = {0.f, 0.f, 0.f, 0.f};
            cf = __builtin_amdgcn_mfma_f32_16x16x32_f16(a0, bb0, cf, 0, 0, 0);
            cf = __builtin_amdgcn_mfma_f32_16x16x32_f16(a1, bb1, cf, 0, 0, 0);
            accp[tt] = cf;
        }
        #pragma unroll
        for (int r = 0; r < 4; ++r) {
            int orow = rbase + q * 4 + r;
            if (orow < N_NODES) {
                #pragma unroll
                for (int tt = 0; tt < 4; ++tt)
                    yh[(size_t)orow * DIM + tt * 16 + m] = (_Float16)accp[tt][r];
            }
        }
    }
}

// ---------------------------------------------------------------------------
// Fused bin + gather (projected space).  Grid 784 x 512; block b handles half
// half=(b>>3)&1 of bucket (b>>4)*8+(b&7) (sibling pair (b, b^8) -> same XCD:
// bucket list fetched into one L2).
//  1. ONE scan pass -> per-node slot arrays (LDS atomic slot alloc).
//  2. 64 groups x 8 lanes, 1 node/group, single pass: 8 edges in flight,
//     half8 fp16 gather of y-rows, fp32 register accumulate, then
//     out = relu((acc + y_self + bias) / deg) stored directly as float4
//     (8 lanes x 32 B = 256 B contiguous per node).  No MFMA phase, no
//     pooled LDS tile, no second barrier.  LDS 16.3 KB; ~6 waves/SIMD
//     resident (vs ~3 before) to hide the random-gather latency.
// ---------------------------------------------------------------------------
__global__ void __launch_bounds__(512, 6) fused_kernel(
        const _Float16* __restrict__ yh,
        const float* __restrict__ bias,
        const float* __restrict__ deg,
        const int* __restrict__ cursor,
        const unsigned int* __restrict__ coarse,
        float* __restrict__ out) {
    __shared__ int sedges[64 * BINCAP];    // 16 KB
    __shared__ int cur[64];

    int t = threadIdx.x;
    int b = blockIdx.x;
    int bucket = (b >> 4) * 8 + (b & 7);   // pair (b, b^8) -> same bucket+XCD
    int half = (b >> 3) & 1;
    if (bucket >= CB) return;              // block-uniform early-out
    int nb = bucket * 128 + half * 64;     // global node base for this block
    int cnt = cursor[bucket];
    const unsigned int* cbk = coarse + (size_t)bucket * CAP;

    if (t < 64) cur[t] = 0;
    __syncthreads();

    // --- 1. one-pass binned scatter ---
    for (int i = t; i < cnt; i += 512) {
        unsigned int e = cbk[i];
        int loc = (int)(e & 127u);
        if ((loc >> 6) == half) {
            int bin = loc & 63;
            int p = atomicAdd(&cur[bin], 1);
            sedges[bin * BINCAP + p] = (int)(e >> 7);
        }
    }
    __syncthreads();

    // --- 2. gather in projected space: 64 groups of 8 lanes, 1 node each ---
    int g = t >> 3;          // group 0..63 = local node
    int c = t & 7;           // half8 chunk within the 64-wide row
    int node = nb + g;

    float bj[8];
    *reinterpret_cast<float4*>(&bj[0]) = reinterpret_cast<const float4*>(bias)[c * 2];
    *reinterpret_cast<float4*>(&bj[4]) = reinterpret_cast<const float4*>(bias)[c * 2 + 1];

    float acc[8];
    #pragma unroll
    for (int j = 0; j < 8; ++j) acc[j] = 0.f;
    const int* bp = &sedges[g * BINCAP];
    int ct = cur[g];                        // 0 for nodes >= N (no edges)
    int k = 0;
    for (; k + 8 <= ct; k += 8) {           // 8 edges in flight
        int sid[8];
        #pragma unroll
        for (int u = 0; u < 8; ++u) sid[u] = bp[k + u];
        half8 v[8];
        #pragma unroll
        for (int u = 0; u < 8; ++u)
            v[u] = *reinterpret_cast<const half8*>(yh + (size_t)sid[u] * DIM + c * 8);
        #pragma unroll
        for (int u = 0; u < 8; ++u) {
            #pragma unroll
            for (int j = 0; j < 8; ++j) acc[j] += (float)v[u][j];
        }
    }
    for (; k + 4 <= ct; k += 4) {           // 4-wide tail
        int sid[4];
        #pragma unroll
        for (int u = 0; u < 4; ++u) sid[u] = bp[k + u];
        half8 v[4];
        #pragma unroll
        for (int u = 0; u < 4; ++u)
            v[u] = *reinterpret_cast<const half8*>(yh + (size_t)sid[u] * DIM + c * 8);
        #pragma unroll
        for (int u = 0; u < 4; ++u) {
            #pragma unroll
            for (int j = 0; j < 8; ++j) acc[j] += (float)v[u][j];
        }
    }
    for (; k < ct; ++k) {
        int s0 = bp[k];
        half8 v0 = *reinterpret_cast<const half8*>(yh + (size_t)s0 * DIM + c * 8);
        #pragma unroll
        for (int j = 0; j < 8; ++j) acc[j] += (float)v0[j];
    }

    if (node < N_NODES) {
        half8 r = *reinterpret_cast<const half8*>(yh + (size_t)node * DIM + c * 8);
        float inv = 1.0f / deg[node];
        float o[8];
        #pragma unroll
        for (int j = 0; j < 8; ++j)
            o[j] = fmaxf((acc[j] + (float)r[j] + bj[j]) * inv, 0.f);
        float4* op = reinterpret_cast<float4*>(out + (size_t)node * DIM + c * 8);
        op[0] = make_float4(o[0], o[1], o[2], o[3]);
        op[1] = make_float4(o[4], o[5], o[6], o[7]);
    }
}

extern "C" void kernel_launch(void* const* d_in, const int* in_sizes, int n_in,
                              void* d_out, int out_size, void* d_ws, size_t ws_size,
                              hipStream_t stream) {
    const float* x        = (const float*)d_in[0];
    const float* weight   = (const float*)d_in[1];
    const float* bias     = (const float*)d_in[2];
    const float* node_deg = (const float*)d_in[3];
    const int*   edge_src = (const int*)d_in[4];
    const int*   edge_dst = (const int*)d_in[5];
    float* out = (float*)d_out;
    const int E = in_sizes[4];

    char* ws = (char*)d_ws;
    int*          cursor = (int*)(ws + WS_CURSOR);
    unsigned int* coarse = (unsigned int*)(ws + WS_COARSE);
    _Float16*     yh     = (_Float16*)(ws + WS_YH);

    hipMemsetAsync(cursor, 0, CB * sizeof(int), stream);

    int pa = (E + EB - 1) / EB;               // 131 partition blocks
    prep_kernel<<<pa + 391, 512, 0, stream>>>(
        x, weight, edge_src, edge_dst, cursor, coarse, yh, E, pa);

    fused_kernel<<<784, 512, 0, stream>>>(
        yh, bias, node_deg, cursor, coarse, out);
}

// Round 2
// 105.218 us; speedup vs baseline: 1.0775x; 1.0405x over previous
//
#include <hip/hip_runtime.h>
#include <hip/hip_fp16.h>

#define N_NODES 50000
#define DIM 64
#define CB 782          // buckets = ceil(N/64); bucket = dst >> 6
#define CAP 1280        // per-bucket capacity (mean 1023, sd ~32 -> +8 sd)
#define EPT 12          // edges per thread in partition (register-staged)
#define EB (512 * EPT)  // 6144 edges per partition block -> 131 blocks
#define BINCAP 64       // per-node LDS edge slots (deg: mean 16 sd 4 -> z=12)

typedef _Float16 half8 __attribute__((ext_vector_type(8)));
typedef float floatx4 __attribute__((ext_vector_type(4)));

// Workspace byte offsets (16B-aligned).
#define WS_CURSOR  0                          // CB ints (4 KB reserved)
#define WS_COARSE  4096                       // CB*CAP uint = 4,003,840
#define WS_YH      (WS_COARSE + 4003840)      // N*DIM f16 = 6,400,000 (y = x@W)

// ---------------------------------------------------------------------------
// Prep (512 thr): blocks [0,pa): SINGLE-PASS partition (register-staged,
// EPT=12/thread): hist -> reserve -> scatter.  Edge packed (src<<6)|(dst&63).
// Blocks [pa, pa+391): y = x @ W in fp16.  Projection commutes with the
// segment-sum ((agg+x)@W = segsum(x@W)+x@W), so fused needs NO MFMA phase.
// ---------------------------------------------------------------------------
__global__ void __launch_bounds__(512) prep_kernel(
        const float* __restrict__ x, const float* __restrict__ W,
        const int* __restrict__ edge_src, const int* __restrict__ edge_dst,
        int* __restrict__ cursor, unsigned int* __restrict__ coarse,
        _Float16* __restrict__ yh, int E, int pa) {
    int b = blockIdx.x, t = threadIdx.x;
    if (b < pa) {
        __shared__ int lhist[CB];
        __shared__ int lbase[CB];
        for (int i = t; i < CB; i += 512) lhist[i] = 0;
        __syncthreads();

        int base = b * EB;
        unsigned int pk[EPT];
        int bk[EPT];
        #pragma unroll
        for (int j = 0; j < EPT; ++j) {
            int e = base + j * 512 + t;       // coalesced
            bk[j] = -1;
            if (e < E) {
                int s = edge_src[e];
                int d = edge_dst[e];
                bk[j] = d >> 6;
                pk[j] = ((unsigned int)s << 6) | (unsigned int)(d & 63);
                atomicAdd(&lhist[bk[j]], 1);
            }
        }
        __syncthreads();
        for (int i = t; i < CB; i += 512) {
            lbase[i] = atomicAdd(&cursor[i], lhist[i]);
            lhist[i] = 0;
        }
        __syncthreads();
        #pragma unroll
        for (int j = 0; j < EPT; ++j) {
            if (bk[j] >= 0) {
                int r = atomicAdd(&lhist[bk[j]], 1);
                coarse[(size_t)bk[j] * CAP + lbase[bk[j]] + r] = pk[j];
            }
        }
    } else {
        // --- GEMM: yh[row] = fp16(x[row] @ W), 128 rows per block ---
        __shared__ _Float16 wh[64 * 80];      // wh[n*80+k] = W[k][n], 10.24 KB
        #pragma unroll
        for (int i = 0; i < 8; ++i) {
            int idx = i * 512 + t;            // coalesced read of W
            int k = idx >> 6, n = idx & 63;
            wh[n * 80 + k] = (_Float16)W[idx];
        }
        __syncthreads();

        int wv = t >> 6, lane = t & 63;
        int m = lane & 15, q = lane >> 4;
        int rbase = (b - pa) * 128 + wv * 16;
        int row = rbase + m;
        int rowc = row < N_NODES ? row : N_NODES - 1;   // clamp OOB loads
        const float* xp = x + (size_t)rowc * DIM + q * 8;
        float4 f0 = *reinterpret_cast<const float4*>(xp);
        float4 f1 = *reinterpret_cast<const float4*>(xp + 4);
        float4 f2 = *reinterpret_cast<const float4*>(xp + 32);
        float4 f3 = *reinterpret_cast<const float4*>(xp + 36);
        half8 a0 = {(_Float16)f0.x, (_Float16)f0.y, (_Float16)f0.z, (_Float16)f0.w,
                    (_Float16)f1.x, (_Float16)f1.y, (_Float16)f1.z, (_Float16)f1.w};
        half8 a1 = {(_Float16)f2.x, (_Float16)f2.y, (_Float16)f2.z, (_Float16)f2.w,
                    (_Float16)f3.x, (_Float16)f3.y, (_Float16)f3.z, (_Float16)f3.w};

        floatx4 accp[4];
        #pragma unroll
        for (int tt = 0; tt < 4; ++tt) {
            half8 bb0 = *reinterpret_cast<const half8*>(&wh[(tt * 16 + m) * 80 + q * 8]);
            half8 bb1 = *reinterpret_cast<const half8*>(&wh[(tt * 16 + m) * 80 + 32 + q * 8]);
            floatx4 cf = {0.f, 0.f, 0.f, 0.f};
            cf = __builtin_amdgcn_mfma_f32_16x16x32_f16(a0, bb0, cf, 0, 0, 0);
            cf = __builtin_amdgcn_mfma_f32_16x16x32_f16(a1, bb1, cf, 0, 0, 0);
            accp[tt] = cf;
        }
        #pragma unroll
        for (int r = 0; r < 4; ++r) {
            int orow = rbase + q * 4 + r;
            if (orow < N_NODES) {
                #pragma unroll
                for (int tt = 0; tt < 4; ++tt)
                    yh[(size_t)orow * DIM + tt * 16 + m] = (_Float16)accp[tt][r];
            }
        }
    }
}

// ---------------------------------------------------------------------------
// Fused bin + gather (projected space).  Grid CB x 512; block = one 64-node
// bucket (no sibling halving: each coarse list is scanned exactly once).
//  1. ONE scan pass -> per-node slot arrays (LDS atomic slot alloc).
//  2. 64 groups x 8 lanes, 1 node/group: 8 edges in flight, half8 fp16
//     gather of y-rows, 3-level fp16 pairwise-tree reduce (v_pk_add_f16,
//     ~44 VALU ops/batch vs 128 for cvt+add-all) then one fp32 fold; then
//     out = relu((acc + y_self + bias) / deg) stored as 2x float4.
//     No MFMA phase, no pooled tile, no second barrier; ~6 waves/SIMD.
// ---------------------------------------------------------------------------
__global__ void __launch_bounds__(512, 6) fused_kernel(
        const _Float16* __restrict__ yh,
        const float* __restrict__ bias,
        const float* __restrict__ deg,
        const int* __restrict__ cursor,
        const unsigned int* __restrict__ coarse,
        float* __restrict__ out) {
    __shared__ int sedges[64 * BINCAP];    // 16 KB
    __shared__ int cur[64];

    int t = threadIdx.x;
    int b = blockIdx.x;                    // bucket id
    int nb = b * 64;                       // global node base for this block
    int cnt = cursor[b];
    const unsigned int* cbk = coarse + (size_t)b * CAP;

    if (t < 64) cur[t] = 0;
    __syncthreads();

    // --- 1. one-pass binned scatter (no discard: whole list belongs here) ---
    for (int i = t; i < cnt; i += 512) {
        unsigned int e = cbk[i];
        int bin = (int)(e & 63u);
        int p = atomicAdd(&cur[bin], 1);
        sedges[bin * BINCAP + p] = (int)(e >> 6);
    }
    __syncthreads();

    // --- 2. gather in projected space: 64 groups of 8 lanes, 1 node each ---
    int g = t >> 3;          // group 0..63 = local node
    int c = t & 7;           // half8 chunk within the 64-wide row
    int node = nb + g;

    float bj[8];
    *reinterpret_cast<float4*>(&bj[0]) = reinterpret_cast<const float4*>(bias)[c * 2];
    *reinterpret_cast<float4*>(&bj[4]) = reinterpret_cast<const float4*>(bias)[c * 2 + 1];

    float acc[8];
    #pragma unroll
    for (int j = 0; j < 8; ++j) acc[j] = 0.f;
    const int* bp = &sedges[g * BINCAP];
    int ct = cur[g];                        // 0 for nodes >= N (no edges)
    int k = 0;
    for (; k + 8 <= ct; k += 8) {           // 8 edges in flight
        int sid[8];
        #pragma unroll
        for (int u = 0; u < 8; ++u) sid[u] = bp[k + u];
        half8 v[8];
        #pragma unroll
        for (int u = 0; u < 8; ++u)
            v[u] = *reinterpret_cast<const half8*>(yh + (size_t)sid[u] * DIM + c * 8);
        // 3-level fp16 pairwise tree (v_pk_add_f16), one fp32 fold
        half8 s0 = v[0] + v[1];
        half8 s1 = v[2] + v[3];
        half8 s2 = v[4] + v[5];
        half8 s3 = v[6] + v[7];
        half8 u0 = s0 + s1;
        half8 u1 = s2 + s3;
        half8 w  = u0 + u1;
        #pragma unroll
        for (int j = 0; j < 8; ++j) acc[j] += (float)w[j];
    }
    if (k + 4 <= ct) {                      // 4-wide tail
        int sid[4];
        #pragma unroll
        for (int u = 0; u < 4; ++u) sid[u] = bp[k + u];
        half8 v[4];
        #pragma unroll
        for (int u = 0; u < 4; ++u)
            v[u] = *reinterpret_cast<const half8*>(yh + (size_t)sid[u] * DIM + c * 8);
        half8 s0 = v[0] + v[1];
        half8 s1 = v[2] + v[3];
        half8 u0 = s0 + s1;
        #pragma unroll
        for (int j = 0; j < 8; ++j) acc[j] += (float)u0[j];
        k += 4;
    }
    for (; k < ct; ++k) {
        int s0 = bp[k];
        half8 v0 = *reinterpret_cast<const half8*>(yh + (size_t)s0 * DIM + c * 8);
        #pragma unroll
        for (int j = 0; j < 8; ++j) acc[j] += (float)v0[j];
    }

    if (node < N_NODES) {
        half8 r = *reinterpret_cast<const half8*>(yh + (size_t)node * DIM + c * 8);
        float inv = 1.0f / deg[node];
        float o[8];
        #pragma unroll
        for (int j = 0; j < 8; ++j)
            o[j] = fmaxf((acc[j] + (float)r[j] + bj[j]) * inv, 0.f);
        float4* op = reinterpret_cast<float4*>(out + (size_t)node * DIM + c * 8);
        op[0] = make_float4(o[0], o[1], o[2], o[3]);
        op[1] = make_float4(o[4], o[5], o[6], o[7]);
    }
}

extern "C" void kernel_launch(void* const* d_in, const int* in_sizes, int n_in,
                              void* d_out, int out_size, void* d_ws, size_t ws_size,
                              hipStream_t stream) {
    const float* x        = (const float*)d_in[0];
    const float* weight   = (const float*)d_in[1];
    const float* bias     = (const float*)d_in[2];
    const float* node_deg = (const float*)d_in[3];
    const int*   edge_src = (const int*)d_in[4];
    const int*   edge_dst = (const int*)d_in[5];
    float* out = (float*)d_out;
    const int E = in_sizes[4];

    char* ws = (char*)d_ws;
    int*          cursor = (int*)(ws + WS_CURSOR);
    unsigned int* coarse = (unsigned int*)(ws + WS_COARSE);
    _Float16*     yh     = (_Float16*)(ws + WS_YH);

    hipMemsetAsync(cursor, 0, CB * sizeof(int), stream);

    int pa = (E + EB - 1) / EB;               // 131 partition blocks
    prep_kernel<<<pa + 391, 512, 0, stream>>>(
        x, weight, edge_src, edge_dst, cursor, coarse, yh, E, pa);

    fused_kernel<<<CB, 512, 0, stream>>>(
        yh, bias, node_deg, cursor, coarse, out);
}

// Round 3
// 102.728 us; speedup vs baseline: 1.1036x; 1.0242x over previous
//
#include <hip/hip_runtime.h>
#include <hip/hip_fp16.h>

#define N_NODES 50000
#define DIM 64
#define CB 782          // buckets = ceil(N/64); bucket = dst >> 6
#define CAP 1280        // per-bucket capacity (mean 1023, sd ~32 -> +8 sd)
#define EPT 12          // edges per thread in partition (register-staged)
#define EB (512 * EPT)  // 6144 edges per partition block -> 131 blocks
#define BINCAP 64       // per-node LDS edge slots (deg: mean 16 sd 4 -> z=12)
#define ZROW N_NODES    // sentinel node: yh row 50000 is all zeros (pad slots)

typedef _Float16 half8 __attribute__((ext_vector_type(8)));
typedef float floatx4 __attribute__((ext_vector_type(4)));

// Workspace byte offsets (16B-aligned).
#define WS_CURSOR  0                          // CB ints (4 KB reserved)
#define WS_COARSE  4096                       // CB*CAP uint = 4,003,840
#define WS_YH      (WS_COARSE + 4003840)      // 50048*DIM f16 = 6,406,144

// ---------------------------------------------------------------------------
// Prep (512 thr): blocks [0,pa): SINGLE-PASS partition (register-staged,
// EPT=12/thread, int4-vectorized edge loads): hist -> reserve -> scatter.
// Edge packed (src<<6)|(dst&63).  Blocks [pa, pa+391): y = x @ W in fp16
// ((agg+x)@W = segsum(x@W)+x@W, so fused needs NO MFMA phase); rows
// [N, 50048) are written as ZEROS -> row 50000 is the gather pad sentinel.
// ---------------------------------------------------------------------------
__global__ void __launch_bounds__(512) prep_kernel(
        const float* __restrict__ x, const float* __restrict__ W,
        const int* __restrict__ edge_src, const int* __restrict__ edge_dst,
        int* __restrict__ cursor, unsigned int* __restrict__ coarse,
        _Float16* __restrict__ yh, int E, int pa) {
    int b = blockIdx.x, t = threadIdx.x;
    if (b < pa) {
        __shared__ int lhist[CB];
        __shared__ int lbase[CB];
        for (int i = t; i < CB; i += 512) lhist[i] = 0;
        __syncthreads();

        int base = b * EB;
        unsigned int pk[EPT];
        int bk[EPT];
        #pragma unroll
        for (int jj = 0; jj < EPT / 4; ++jj) {      // 16B-vector edge loads
            int e4 = base + jj * 2048 + t * 4;
            if (e4 + 3 < E) {
                int4 s4 = *reinterpret_cast<const int4*>(edge_src + e4);
                int4 d4 = *reinterpret_cast<const int4*>(edge_dst + e4);
                int ss[4] = {s4.x, s4.y, s4.z, s4.w};
                int dd[4] = {d4.x, d4.y, d4.z, d4.w};
                #pragma unroll
                for (int u = 0; u < 4; ++u) {
                    int j = jj * 4 + u;
                    bk[j] = dd[u] >> 6;
                    pk[j] = ((unsigned int)ss[u] << 6) | (unsigned int)(dd[u] & 63);
                    atomicAdd(&lhist[bk[j]], 1);
                }
            } else {
                #pragma unroll
                for (int u = 0; u < 4; ++u) {
                    int j = jj * 4 + u;
                    int e = e4 + u;
                    bk[j] = -1;
                    if (e < E) {
                        int s = edge_src[e];
                        int d = edge_dst[e];
                        bk[j] = d >> 6;
                        pk[j] = ((unsigned int)s << 6) | (unsigned int)(d & 63);
                        atomicAdd(&lhist[bk[j]], 1);
                    }
                }
            }
        }
        __syncthreads();
        for (int i = t; i < CB; i += 512) {
            lbase[i] = atomicAdd(&cursor[i], lhist[i]);
            lhist[i] = 0;
        }
        __syncthreads();
        #pragma unroll
        for (int j = 0; j < EPT; ++j) {
            if (bk[j] >= 0) {
                int r = atomicAdd(&lhist[bk[j]], 1);
                coarse[(size_t)bk[j] * CAP + lbase[bk[j]] + r] = pk[j];
            }
        }
    } else {
        // --- GEMM: yh[row] = fp16(x[row] @ W), 128 rows per block ---
        __shared__ _Float16 wh[64 * 80];      // wh[n*80+k] = W[k][n], 10.24 KB
        #pragma unroll
        for (int i = 0; i < 8; ++i) {
            int idx = i * 512 + t;            // coalesced read of W
            int k = idx >> 6, n = idx & 63;
            wh[n * 80 + k] = (_Float16)W[idx];
        }
        __syncthreads();

        int wv = t >> 6, lane = t & 63;
        int m = lane & 15, q = lane >> 4;
        int rbase = (b - pa) * 128 + wv * 16;
        int row = rbase + m;
        int rowc = row < N_NODES ? row : N_NODES - 1;   // clamp OOB loads
        const float* xp = x + (size_t)rowc * DIM + q * 8;
        float4 f0 = *reinterpret_cast<const float4*>(xp);
        float4 f1 = *reinterpret_cast<const float4*>(xp + 4);
        float4 f2 = *reinterpret_cast<const float4*>(xp + 32);
        float4 f3 = *reinterpret_cast<const float4*>(xp + 36);
        half8 a0 = {(_Float16)f0.x, (_Float16)f0.y, (_Float16)f0.z, (_Float16)f0.w,
                    (_Float16)f1.x, (_Float16)f1.y, (_Float16)f1.z, (_Float16)f1.w};
        half8 a1 = {(_Float16)f2.x, (_Float16)f2.y, (_Float16)f2.z, (_Float16)f2.w,
                    (_Float16)f3.x, (_Float16)f3.y, (_Float16)f3.z, (_Float16)f3.w};

        floatx4 accp[4];
        #pragma unroll
        for (int tt = 0; tt < 4; ++tt) {
            half8 bb0 = *reinterpret_cast<const half8*>(&wh[(tt * 16 + m) * 80 + q * 8]);
            half8 bb1 = *reinterpret_cast<const half8*>(&wh[(tt * 16 + m) * 80 + 32 + q * 8]);
            floatx4 cf = {0.f, 0.f, 0.f, 0.f};
            cf = __builtin_amdgcn_mfma_f32_16x16x32_f16(a0, bb0, cf, 0, 0, 0);
            cf = __builtin_amdgcn_mfma_f32_16x16x32_f16(a1, bb1, cf, 0, 0, 0);
            accp[tt] = cf;
        }
        #pragma unroll
        for (int r = 0; r < 4; ++r) {
            int orow = rbase + q * 4 + r;
            if (orow < N_NODES) {
                #pragma unroll
                for (int tt = 0; tt < 4; ++tt)
                    yh[(size_t)orow * DIM + tt * 16 + m] = (_Float16)accp[tt][r];
            } else {                          // rows [N, 50048): zero sentinel
                #pragma unroll
                for (int tt = 0; tt < 4; ++tt)
                    yh[(size_t)orow * DIM + tt * 16 + m] = (_Float16)0.f;
            }
        }
    }
}

// ---------------------------------------------------------------------------
// Fused bin + gather (projected space).  Grid CB x 512; block = one 64-node
// bucket.
//  1. ONE scan pass -> per-node slot arrays (LDS atomic slot alloc).
//  2. Pad each slot list to a multiple of 8 with ZROW (zero row) -> gather
//     is ONLY uniform 8-wide batches: 2x ds_read_b128 slot fetch (broadcast),
//     8 half8 gathers in flight, 3-level fp16 pairwise tree, one fp32 fold.
//     No 4-tail, no scalar tail, no divergent branches.  Then
//     out = relu((acc + y_self + bias) / deg) stored as 2x float4.
// ---------------------------------------------------------------------------
__global__ void __launch_bounds__(512, 6) fused_kernel(
        const _Float16* __restrict__ yh,
        const float* __restrict__ bias,
        const float* __restrict__ deg,
        const int* __restrict__ cursor,
        const unsigned int* __restrict__ coarse,
        float* __restrict__ out) {
    __shared__ int sedges[64 * BINCAP];    // 16 KB
    __shared__ int cur[64];

    int t = threadIdx.x;
    int b = blockIdx.x;                    // bucket id
    int nb = b * 64;                       // global node base for this block
    int cnt = cursor[b];
    const unsigned int* cbk = coarse + (size_t)b * CAP;

    if (t < 64) cur[t] = 0;
    __syncthreads();

    // --- 1. one-pass binned scatter (whole list belongs to this block) ---
    for (int i = t; i < cnt; i += 512) {
        unsigned int e = cbk[i];
        int bin = (int)(e & 63u);
        int p = atomicAdd(&cur[bin], 1);
        sedges[bin * BINCAP + p] = (int)(e >> 6);
    }
    __syncthreads();

    int g = t >> 3;          // group 0..63 = local node
    int c = t & 7;           // half8 chunk within the 64-wide row

    // --- 1b. pad each list to a multiple of 8 with the zero-row sentinel ---
    {
        int cc = cur[g];
        int s = cc + c;
        if (s < ((cc + 7) & ~7) && s < BINCAP)
            sedges[g * BINCAP + s] = ZROW;
    }
    __syncthreads();

    // --- 2. gather in projected space: uniform 8-wide batches only ---
    int node = nb + g;

    float bj[8];
    *reinterpret_cast<float4*>(&bj[0]) = reinterpret_cast<const float4*>(bias)[c * 2];
    *reinterpret_cast<float4*>(&bj[4]) = reinterpret_cast<const float4*>(bias)[c * 2 + 1];

    float acc[8];
    #pragma unroll
    for (int j = 0; j < 8; ++j) acc[j] = 0.f;
    const int* bp = &sedges[g * BINCAP];
    int ct8 = (cur[g] + 7) & ~7;            // 0 for nodes >= N (no edges)
    for (int k = 0; k < ct8; k += 8) {      // 8 edges in flight, no tails
        int4 sa = *reinterpret_cast<const int4*>(bp + k);       // broadcast
        int4 sb = *reinterpret_cast<const int4*>(bp + k + 4);   // ds_read_b128
        int sid[8] = {sa.x, sa.y, sa.z, sa.w, sb.x, sb.y, sb.z, sb.w};
        half8 v[8];
        #pragma unroll
        for (int u = 0; u < 8; ++u)
            v[u] = *reinterpret_cast<const half8*>(yh + (size_t)sid[u] * DIM + c * 8);
        // 3-level fp16 pairwise tree (v_pk_add_f16), one fp32 fold
        half8 s0 = v[0] + v[1];
        half8 s1 = v[2] + v[3];
        half8 s2 = v[4] + v[5];
        half8 s3 = v[6] + v[7];
        half8 u0 = s0 + s1;
        half8 u1 = s2 + s3;
        half8 w  = u0 + u1;
        #pragma unroll
        for (int j = 0; j < 8; ++j) acc[j] += (float)w[j];
    }

    if (node < N_NODES) {
        half8 r = *reinterpret_cast<const half8*>(yh + (size_t)node * DIM + c * 8);
        float inv = 1.0f / deg[node];
        float o[8];
        #pragma unroll
        for (int j = 0; j < 8; ++j)
            o[j] = fmaxf((acc[j] + (float)r[j] + bj[j]) * inv, 0.f);
        float4* op = reinterpret_cast<float4*>(out + (size_t)node * DIM + c * 8);
        op[0] = make_float4(o[0], o[1], o[2], o[3]);
        op[1] = make_float4(o[4], o[5], o[6], o[7]);
    }
}

extern "C" void kernel_launch(void* const* d_in, const int* in_sizes, int n_in,
                              void* d_out, int out_size, void* d_ws, size_t ws_size,
                              hipStream_t stream) {
    const float* x        = (const float*)d_in[0];
    const float* weight   = (const float*)d_in[1];
    const float* bias     = (const float*)d_in[2];
    const float* node_deg = (const float*)d_in[3];
    const int*   edge_src = (const int*)d_in[4];
    const int*   edge_dst = (const int*)d_in[5];
    float* out = (float*)d_out;
    const int E = in_sizes[4];

    char* ws = (char*)d_ws;
    int*          cursor = (int*)(ws + WS_CURSOR);
    unsigned int* coarse = (unsigned int*)(ws + WS_COARSE);
    _Float16*     yh     = (_Float16*)(ws + WS_YH);

    hipMemsetAsync(cursor, 0, CB * sizeof(int), stream);

    int pa = (E + EB - 1) / EB;               // 131 partition blocks
    prep_kernel<<<pa + 391, 512, 0, stream>>>(
        x, weight, edge_src, edge_dst, cursor, coarse, yh, E, pa);

    fused_kernel<<<CB, 512, 0, stream>>>(
        yh, bias, node_deg, cursor, coarse, out);
}